// Round 8
// baseline (374.569 us; speedup 1.0000x reference)
//
#include <hip/hip_runtime.h>
#include <hip/hip_cooperative_groups.h>
#include <math.h>

namespace cg = cooperative_groups;

#define NPIX 4096
#define KN 20
#define MTOT 327680.0    // B*N*K

__device__ inline unsigned long long shflx64(unsigned long long v, int m) {
  unsigned lo = (unsigned)v, hi = (unsigned)(v >> 32);
  lo = __shfl_xor(lo, m, 64);
  hi = __shfl_xor(hi, m, 64);
  return (((unsigned long long)hi) << 32) | lo;
}

union SMem {
  struct { unsigned long long A[4096]; unsigned long long B[4096]; } srt;  // 64KB
  struct { float x[224]; float c1[7680]; } cv1;                            // 31.6KB
  struct { float c2[5376]; float c3[1920]; } cv3;                          // 29.2KB
  struct { double red[1280]; } f1;                                         // 10KB
  struct { double sred[4][5]; } kn;
  struct { double c2c[3][2]; } ot;
};

// register-tier bitonic exchange with compile-time RJ (avoids dynamic reg indexing)
template<int RJ>
__device__ inline void regstage16(unsigned long long (&key)[16], unsigned k, int l, int wv) {
#pragma unroll
  for (int r = 0; r < 16; r++) {
    int pr = r ^ RJ;
    if (pr > r) {
      unsigned e = ((unsigned)wv << 10) + ((unsigned)r << 6) + (unsigned)l;
      bool up = ((e & k) == 0);
      unsigned long long a = key[r], c = key[pr];
      bool sw = up ? (c < a) : (c > a);
      if (sw) { key[r] = c; key[pr] = a; }
    }
  }
}

__global__ __launch_bounds__(256) void mega_k(
    const float* __restrict__ x,
    const float* __restrict__ c1w, const float* __restrict__ c1b,
    const float* __restrict__ c2w, const float* __restrict__ c2b,
    const float* __restrict__ c3w, const float* __restrict__ c3b,
    const float* __restrict__ c4w, const float* __restrict__ c4b,
    const float* __restrict__ ew1, const float* __restrict__ eb1,
    const float* __restrict__ eg1, const float* __restrict__ ebt1,
    const float* __restrict__ ew2, const float* __restrict__ eb2,
    const float* __restrict__ eg2, const float* __restrict__ ebt2,
    float* __restrict__ out, float* __restrict__ ws) {
  cg::grid_group grid = cg::this_grid();
  __shared__ SMem sm;

  // workspace layout (float offsets; doubles 8B-aligned)
  float*  c2buf   = ws;                       // 524288
  float*  fbuf    = ws + 524288;              // 16384
  float*  dw      = ws + 540672;              // 327680
  float*  sval    = ws + 868352;              // 16384
  int*    sidx    = (int*)(ws + 884736);      // 16384
  float*  maxo    = ws + 901120;              // 49152
  float*  mino    = ws + 950272;              // 49152
  double* part1   = (double*)(ws + 999424);   // 256*5
  double* part2   = (double*)(ws + 1001984);  // 256*3*2
  float*  consts1 = ws + 1005056;             // 144

  const int tid = threadIdx.x, blk = blockIdx.x;
  const int l = tid & 63, wv = tid >> 6;
  const int b = blk >> 6, tile = blk & 63;
  const int th = (tile >> 3) << 3, tw = (tile & 7) << 3;

  // ================= P0: conv1 (5x5,1->64,tanh) + conv2 (3x3,64->32,tanh) =================
  for (int i = tid; i < 196; i += 256) {
    int r = i / 14, c = i - r*14;
    int gr = th - 3 + r, gc = tw - 3 + c;
    sm.cv1.x[r*16 + c] = (gr>=0 && gr<64 && gc>=0 && gc<64) ? x[b*NPIX + (gr<<6) + gc] : 0.f;
  }
  __syncthreads();
  // conv1 on 10x10 halo region; ZERO outside image (reference zero-pads conv1's OUTPUT)
  for (int half = 0; half < 2; half++) {
    int px = l + (half << 6);
    if (px < 100) {
      int i = px / 10, j = px - i*10;
      int gy = th - 1 + i, gx = tw - 1 + j;
      bool inb = (gy>=0 && gy<64 && gx>=0 && gx<64);
      for (int cc = 0; cc < 16; cc++) {
        int co = (wv << 4) + cc;
        float acc = c1b[co];
#pragma unroll
        for (int di=0; di<5; di++)
#pragma unroll
          for (int dj=0; dj<5; dj++)
            acc = fmaf(sm.cv1.x[(i+di)*16 + j+dj], c1w[co*25 + di*5 + dj], acc);
        sm.cv1.c1[co*120 + i*12 + j] = inb ? tanhf(acc) : 0.f;
      }
    }
  }
  __syncthreads();
  // conv2 on exact 8x8; wave wv -> couts wv*8..+7, lane -> pixel
  {
    int py = l >> 3, px2 = l & 7;
    float acc[8];
#pragma unroll
    for (int o=0;o<8;o++) acc[o] = c2b[(wv<<3) + o];
    for (int cin = 0; cin < 64; cin++) {
      float v[9];
#pragma unroll
      for (int di=0;di<3;di++)
#pragma unroll
        for (int dj=0;dj<3;dj++)
          v[di*3+dj] = sm.cv1.c1[cin*120 + (py+di)*12 + px2+dj];
      const float* wc = c2w + (((wv<<3)*64) + cin)*9;
#pragma unroll
      for (int o=0;o<8;o++)
#pragma unroll
        for (int t=0;t<9;t++)
          acc[o] = fmaf(v[t], wc[o*576 + t], acc[o]);
    }
#pragma unroll
    for (int o=0;o<8;o++)
      c2buf[(((size_t)b*32 + (wv<<3) + o) << 12) + ((th+py)<<6) + (tw+px2)] = tanhf(acc[o]);
  }
  grid.sync();

  // ================= P1: conv3 (3x3,32->16,tanh) + conv4 (3x3,16->1) =================
  for (int i = tid; i < 4608; i += 256) {
    int cin = i / 144, rem = i - cin*144;
    int rr = rem / 12, cc = rem - rr*12;
    int gr = th - 2 + rr, gc = tw - 2 + cc;
    float v = (gr>=0 && gr<64 && gc>=0 && gc<64)
              ? c2buf[(((size_t)b*32 + cin) << 12) + (gr<<6) + gc] : 0.f;
    sm.cv3.c2[cin*168 + rr*14 + cc] = v;
  }
  __syncthreads();
  // conv3 on 10x10 halo region; ZERO outside image (conv4 zero-pads conv3's output)
  for (int half = 0; half < 2; half++) {
    int px = l + (half << 6);
    if (px < 100) {
      int i = px / 10, j = px - i*10;
      int gy = th - 1 + i, gx = tw - 1 + j;
      bool inb = (gy>=0 && gy<64 && gx>=0 && gx<64);
      for (int cc = 0; cc < 4; cc++) {
        int co = (wv << 2) + cc;
        float acc = c3b[co];
        for (int cin = 0; cin < 32; cin++) {
#pragma unroll
          for (int di=0;di<3;di++)
#pragma unroll
            for (int dj=0;dj<3;dj++)
              acc = fmaf(sm.cv3.c2[cin*168 + (i+di)*14 + j+dj],
                         c3w[(co*32+cin)*9 + di*3+dj], acc);
        }
        sm.cv3.c3[co*120 + i*12 + j] = inb ? tanhf(acc) : 0.f;
      }
    }
  }
  __syncthreads();
  if (tid < 64) {
    int py = tid >> 3, px = tid & 7;
    float acc = c4b[0];
    for (int cin = 0; cin < 16; cin++) {
#pragma unroll
      for (int di=0;di<3;di++)
#pragma unroll
        for (int dj=0;dj<3;dj++)
          acc = fmaf(sm.cv3.c3[cin*120 + (py+di)*12 + px+dj], c4w[cin*9 + di*3+dj], acc);
    }
    fbuf[b*NPIX + ((th+py)<<6) + (tw+px)] = acc;
  }
  grid.sync();

  // ================= P2: per-batch 4096-key bitonic sort (blocks 0..3) =================
  if (blk < 4) {
    const float* fb = fbuf + (blk << 12);
    unsigned long long key[16];
#pragma unroll
    for (int r=0;r<16;r++) {
      unsigned e = ((unsigned)wv<<10) + ((unsigned)r<<6) + (unsigned)l;
      float v = fb[e];
      unsigned u = __float_as_uint(v);
      u ^= (u >> 31) ? 0xFFFFFFFFu : 0x80000000u;   // order-preserving flip
      key[r] = (((unsigned long long)u) << 32) | e;
    }
    int cur = 0;
    for (unsigned k = 2; k <= 4096; k <<= 1) {
      for (unsigned j = k >> 1; j > 0; j >>= 1) {
        if (j >= 1024) {
          unsigned long long* buf = cur ? sm.srt.B : sm.srt.A; cur ^= 1;
#pragma unroll
          for (int r=0;r<16;r++) buf[((unsigned)wv<<10)+((unsigned)r<<6)+l] = key[r];
          __syncthreads();
#pragma unroll
          for (int r=0;r<16;r++) {
            unsigned e = ((unsigned)wv<<10)+((unsigned)r<<6)+(unsigned)l;
            unsigned long long a = key[r], p = buf[e ^ j];
            bool up = ((e & k) == 0);
            bool keepmin = ((e & j) == 0) == up;
            key[r] = (keepmin ? (p < a) : (p > a)) ? p : a;
          }
        } else if (j >= 64) {
          switch (j >> 6) {
            case 1: regstage16<1>(key, k, l, wv); break;
            case 2: regstage16<2>(key, k, l, wv); break;
            case 4: regstage16<4>(key, k, l, wv); break;
            default: regstage16<8>(key, k, l, wv); break;
          }
        } else {
#pragma unroll
          for (int r=0;r<16;r++) {
            unsigned e = ((unsigned)wv<<10)+((unsigned)r<<6)+(unsigned)l;
            unsigned long long a = key[r], p = shflx64(a, (int)j);
            bool up = ((e & k) == 0);
            bool keepmin = ((e & j) == 0) == up;
            key[r] = (keepmin ? (p < a) : (p > a)) ? p : a;
          }
        }
      }
    }
#pragma unroll
    for (int r=0;r<16;r++) {
      unsigned e = ((unsigned)wv<<10)+((unsigned)r<<6)+(unsigned)l;
      unsigned u = (unsigned)(key[r] >> 32);
      u ^= (u >> 31) ? 0x80000000u : 0xFFFFFFFFu;   // un-flip
      sval[(blk<<12) + e] = __uint_as_float(u);
      sidx[(blk<<12) + e] = (int)(key[r] & 0xFFFFFFFFu);
    }
  }
  grid.sync();

  // ================= P3: KNN (wave/point, ILP-4) + BN1 moments =================
  {
    int bq = blk >> 6;
    const float* svb = sval + (bq << 12);
    const int*   sib = sidx + (bq << 12);
    const float* fB  = fbuf + (bq << 12);
    double a0=0, a1=0, a2=0, a3=0, a4=0;
    for (int it0 = 0; it0 < 16; it0 += 4) {
      unsigned long long kk[4];
      float fnp[4];
      int   sp[4];
#pragma unroll
      for (int p=0;p<4;p++) {
        int s = ((blk & 63) << 6) + (wv << 4) + it0 + p;
        sp[p] = s;
        float fn = svb[s]; fnp[p] = fn;
        int start = s - 32;
        if (start < 0) start = 0;
        if (start > NPIX - 64) start = NPIX - 64;
        int q = start + l;
        float fm = svb[q];
        int   m  = sib[q];
        float sqn = __fmul_rn(fn, fn);
        float pr  = __fmul_rn(fn, fm);
        float dist = __fsub_rn(__fadd_rn(sqn, __fmul_rn(fm, fm)), __fmul_rn(2.0f, pr));
        unsigned u = __float_as_uint(dist);
        u ^= (u >> 31) ? 0xFFFFFFFFu : 0x80000000u;
        kk[p] = (((unsigned long long)u) << 32) | (unsigned)m;
      }
#pragma unroll
      for (int k = 2; k <= 64; k <<= 1)
#pragma unroll
        for (int j = k >> 1; j > 0; j >>= 1) {
#pragma unroll
          for (int p=0;p<4;p++) {
            unsigned long long pp = shflx64(kk[p], j);
            bool up = ((l & k) == 0);
            bool keepmin = ((l & j) == 0) == up;
            kk[p] = (keepmin ? (pp < kk[p]) : (pp > kk[p])) ? pp : kk[p];
          }
        }
#pragma unroll
      for (int p=0;p<4;p++) {
        int mr = (int)(kk[p] & 0xFFFFFFFFu);
        float fn = fnp[p];
        float d = __fsub_rn(fB[mr], fn);       // knn - x1, rank l
        int n = sib[sp[p]];
        if (l >= 1 && l <= 20)
          dw[(size_t)((bq<<12) + n)*KN + (l-1)] = d;
        float dm = (l >= 1 && l <= 20) ? d : 0.f;
        a2 += (double)dm;
        a3 += (double)dm * (double)dm;
        a4 += (double)fn * (double)dm;
        if (l == 0) { a0 += (double)fn; a1 += (double)fn * (double)fn; }
      }
    }
    double v[5] = {a0, a1, a2, a3, a4};
#pragma unroll
    for (int qi=0; qi<5; qi++)
      for (int off=32; off>0; off>>=1) v[qi] += __shfl_down(v[qi], off, 64);
    if (l == 0)
#pragma unroll
      for (int qi=0; qi<5; qi++) sm.kn.sred[wv][qi] = v[qi];
    __syncthreads();
    if (tid == 0)
#pragma unroll
      for (int qi=0; qi<5; qi++)
        part1[blk*5 + qi] = sm.kn.sred[0][qi]+sm.kn.sred[1][qi]+sm.kn.sred[2][qi]+sm.kn.sred[3][qi];
  }
  grid.sync();

  // ================= P4: BN1 fold (block 0) =================
  if (blk == 0) {
    if (tid < 256)
#pragma unroll
      for (int q=0;q<5;q++) sm.f1.red[tid*5+q] = part1[tid*5+q];
    __syncthreads();
    for (int st = 128; st > 0; st >>= 1) {
      if (tid < st)
#pragma unroll
        for (int q=0;q<5;q++) sm.f1.red[tid*5+q] += sm.f1.red[(tid+st)*5+q];
      __syncthreads();
    }
    if (tid < 48) {
      double Ef = sm.f1.red[0]/16384.0, Eff = sm.f1.red[1]/16384.0;
      double Ed = sm.f1.red[2]/MTOT, Edd = sm.f1.red[3]/MTOT, Efd = sm.f1.red[4]/MTOT;
      double Vf = Eff - Ef*Ef, Vd = Edd - Ed*Ed, Cfd = Efd - Ef*Ed;
      int idx = tid;
      double w0 = (double)ew1[idx*2+0], w1 = (double)ew1[idx*2+1];
      double b1 = (double)eb1[idx];
      double m1 = w0*Ef + w1*Ed + b1;
      double v1 = w0*w0*Vf + 2.0*w0*w1*Cfd + w1*w1*Vd;
      double r1 = 1.0 / sqrt(v1 + 1e-5);
      double g = (double)eg1[idx];
      consts1[idx*3+0] = (float)(g*r1*w0);
      consts1[idx*3+1] = (float)(g*r1*w1);
      consts1[idx*3+2] = (float)(g*r1*(b1 - m1) + (double)ebt1[idx]);
    }
  }
  grid.sync();

  // ================= P5: per-branch o_pre max/min + BN2 moments =================
  if (wv < 3) {
    int br = wv;
    int row = (blk << 6) + l;
    float sA[16], sB[16], sC[16], sW[16];
#pragma unroll
    for (int c=0;c<16;c++) {
      int idx = br*16 + c;
      sA[c] = consts1[idx*3+0];
      sB[c] = consts1[idx*3+1];
      sC[c] = consts1[idx*3+2];
      sW[c] = ew2[idx];
    }
    float fv = fbuf[row];
    const float* dd = dw + (size_t)row*KN;
    float b2 = eb2[br];
    float P[16];
#pragma unroll
    for (int c=0;c<16;c++) P[c] = fmaf(sA[c], fv, sC[c]);
    float mx = -INFINITY, mn = INFINITY;
    double s = 0.0, s2 = 0.0;
    for (int k=0;k<KN;k++) {
      float d = dd[k];
      float t = b2;
#pragma unroll
      for (int c=0;c<16;c++)
        t = fmaf(sW[c], fmaxf(fmaf(sB[c], d, P[c]), 0.f), t);
      mx = fmaxf(mx, t);
      mn = fminf(mn, t);
      double td = (double)t;
      s += td; s2 += td*td;
    }
    maxo[br*16384 + row] = mx;
    mino[br*16384 + row] = mn;
#pragma unroll
    for (int off=32; off>0; off>>=1) {
      s  += __shfl_down(s, off, 64);
      s2 += __shfl_down(s2, off, 64);
    }
    if (l == 0) {
      part2[(br*256 + blk)*2 + 0] = s;
      part2[(br*256 + blk)*2 + 1] = s2;
    }
  }
  grid.sync();

  // ================= P6: BN2 fold (per block) + pixel shuffle + sigmoid =================
  if (wv < 3) {
    int br = wv;
    double s = 0.0, s2 = 0.0;
#pragma unroll
    for (int t4=0; t4<4; t4++) {
      int bb = l + (t4 << 6);
      s  += part2[(br*256 + bb)*2 + 0];
      s2 += part2[(br*256 + bb)*2 + 1];
    }
#pragma unroll
    for (int off=32; off>0; off>>=1) {
      s  += __shfl_down(s, off, 64);
      s2 += __shfl_down(s2, off, 64);
    }
    if (l == 0) {
      double mean = s / MTOT;
      double var = s2 / MTOT - mean*mean;
      double r2 = 1.0 / sqrt(var + 1e-5);
      double sc = (double)eg2[br] * r2;
      sm.ot.c2c[br][0] = sc;
      sm.ot.c2c[br][1] = (double)ebt2[br] - sc*mean;
    }
  }
  __syncthreads();
  {
    int tg = (blk << 8) + tid;     // 65536
    int bo = tg >> 14;
    int y = (tg >> 7) & 127, xx = tg & 127;
    int n = ((y>>1)<<6) + (xx>>1);
    int ch = ((y&1)<<1) + (xx&1);
    float v;
    if (ch == 0) {
      v = fbuf[bo*NPIX + n];
    } else {
      int br = ch - 1;
      float sc = (float)sm.ot.c2c[br][0], sh = (float)sm.ot.c2c[br][1];
      float base = (sc >= 0.f) ? maxo[br*16384 + bo*NPIX + n]
                               : mino[br*16384 + bo*NPIX + n];
      v = fmaxf(fmaf(sc, base, sh), 0.f);
    }
    out[tg] = 1.f / (1.f + expf(-v));
  }
}

extern "C" void kernel_launch(void* const* d_in, const int* in_sizes, int n_in,
                              void* d_out, int out_size, void* d_ws, size_t ws_size,
                              hipStream_t stream) {
  (void)in_sizes; (void)n_in; (void)out_size; (void)ws_size;
  const float* x    = (const float*)d_in[0];
  const float* c1w  = (const float*)d_in[1];
  const float* c1b  = (const float*)d_in[2];
  const float* c2w  = (const float*)d_in[3];
  const float* c2b  = (const float*)d_in[4];
  const float* c3w  = (const float*)d_in[5];
  const float* c3b  = (const float*)d_in[6];
  const float* c4w  = (const float*)d_in[7];
  const float* c4b  = (const float*)d_in[8];
  const float* ew1  = (const float*)d_in[9];
  const float* eb1  = (const float*)d_in[10];
  const float* eg1  = (const float*)d_in[11];
  const float* ebt1 = (const float*)d_in[12];
  const float* ew2  = (const float*)d_in[13];
  const float* eb2  = (const float*)d_in[14];
  const float* eg2  = (const float*)d_in[15];
  const float* ebt2 = (const float*)d_in[16];
  float* out = (float*)d_out;
  float* ws  = (float*)d_ws;

  void* args[] = {
    (void*)&x, (void*)&c1w, (void*)&c1b, (void*)&c2w, (void*)&c2b,
    (void*)&c3w, (void*)&c3b, (void*)&c4w, (void*)&c4b,
    (void*)&ew1, (void*)&eb1, (void*)&eg1, (void*)&ebt1,
    (void*)&ew2, (void*)&eb2, (void*)&eg2, (void*)&ebt2,
    (void*)&out, (void*)&ws
  };
  hipLaunchCooperativeKernel((void*)mega_k, dim3(256), dim3(256), args, 0, stream);
}

// Round 9
// 266.779 us; speedup vs baseline: 1.4040x; 1.4040x over previous
//
#include <hip/hip_runtime.h>
#include <hip/hip_cooperative_groups.h>
#include <math.h>

namespace cg = cooperative_groups;

#define NPIX 4096
#define KN 20
#define MTOT 327680.0    // B*N*K

__device__ inline unsigned long long shflx64(unsigned long long v, int m) {
  unsigned lo = (unsigned)v, hi = (unsigned)(v >> 32);
  lo = __shfl_xor(lo, m, 64);
  hi = __shfl_xor(hi, m, 64);
  return (((unsigned long long)hi) << 32) | lo;
}

union SMem {
  struct { unsigned long long A[4096]; unsigned long long B[4096]; } srt;   // 64KB
  struct { float x[224]; float c1[7680]; } cv1;                             // 31.6KB
  struct { float c2[5376]; float c3[1920]; } cv3;                           // 29.2KB
  struct { double red[1280]; float cons[144]; } f1;                         // 10.8KB
  struct { double sred[16][5]; } kn;                                        // 640B
  struct { double c2c[3][2]; } ot;
};

__global__ __launch_bounds__(1024) void mega_k(
    const float* __restrict__ x,
    const float* __restrict__ c1w, const float* __restrict__ c1b,
    const float* __restrict__ c2w, const float* __restrict__ c2b,
    const float* __restrict__ c3w, const float* __restrict__ c3b,
    const float* __restrict__ c4w, const float* __restrict__ c4b,
    const float* __restrict__ ew1, const float* __restrict__ eb1,
    const float* __restrict__ eg1, const float* __restrict__ ebt1,
    const float* __restrict__ ew2, const float* __restrict__ eb2,
    const float* __restrict__ eg2, const float* __restrict__ ebt2,
    float* __restrict__ out, float* __restrict__ ws) {
  cg::grid_group grid = cg::this_grid();
  __shared__ SMem sm;

  // workspace layout (float offsets; doubles 8B-aligned)
  float*  c2buf   = ws;                       // 524288
  float*  fbuf    = ws + 524288;              // 16384
  float*  dw      = ws + 540672;              // 327680
  float*  sval    = ws + 868352;              // 16384
  int*    sidx    = (int*)(ws + 884736);      // 16384
  float*  maxo    = ws + 901120;              // 49152
  float*  mino    = ws + 950272;              // 49152
  double* part1   = (double*)(ws + 999424);   // 256*5
  double* part2   = (double*)(ws + 1001984);  // 256*3*2

  const int tid = threadIdx.x, blk = blockIdx.x;
  const int l = tid & 63, wv = tid >> 6;      // 16 waves
  const int b = blk >> 6, tile = blk & 63;
  const int th = (tile >> 3) << 3, tw = (tile & 7) << 3;

  // ================= P0: conv1 (5x5,1->64,tanh, halo, zero-outside) + conv2 =================
  for (int i = tid; i < 196; i += 1024) {
    int r = i / 14, c = i - r*14;
    int gr = th - 3 + r, gc = tw - 3 + c;
    sm.cv1.x[r*16 + c] = (gr>=0 && gr<64 && gc>=0 && gc<64) ? x[b*NPIX + (gr<<6) + gc] : 0.f;
  }
  __syncthreads();
  // conv1 on 10x10 halo; wave wv -> couts wv*4..+3; lanes cover 100 px in 2 halves
  for (int half = 0; half < 2; half++) {
    int px = l + (half << 6);
    if (px < 100) {
      int i = px / 10, j = px - i*10;
      int gy = th - 1 + i, gx = tw - 1 + j;
      bool inb = (gy>=0 && gy<64 && gx>=0 && gx<64);
      for (int cc = 0; cc < 4; cc++) {
        int co = (wv << 2) + cc;
        float acc = c1b[co];
#pragma unroll
        for (int di=0; di<5; di++)
#pragma unroll
          for (int dj=0; dj<5; dj++)
            acc = fmaf(sm.cv1.x[(i+di)*16 + j+dj], c1w[co*25 + di*5 + dj], acc);
        sm.cv1.c1[co*120 + i*12 + j] = inb ? tanhf(acc) : 0.f;
      }
    }
  }
  __syncthreads();
  // conv2 exact 8x8: thread -> pixel (tid&63), couts og*2..+1 (og = tid>>6)
  {
    int py = (tid & 63) >> 3, px2 = tid & 7;
    int og = tid >> 6;
    int co0 = og << 1;
    float acc[2];
#pragma unroll
    for (int o=0;o<2;o++) acc[o] = c2b[co0 + o];
    for (int cin = 0; cin < 64; cin++) {
      float v[9];
#pragma unroll
      for (int di=0;di<3;di++)
#pragma unroll
        for (int dj=0;dj<3;dj++)
          v[di*3+dj] = sm.cv1.c1[cin*120 + (py+di)*12 + px2+dj];
      const float* wc = c2w + ((co0*64) + cin)*9;
#pragma unroll
      for (int o=0;o<2;o++)
#pragma unroll
        for (int t=0;t<9;t++)
          acc[o] = fmaf(v[t], wc[o*576 + t], acc[o]);
    }
#pragma unroll
    for (int o=0;o<2;o++)
      c2buf[(((size_t)b*32 + co0 + o) << 12) + ((th+py)<<6) + (tw+px2)] = tanhf(acc[o]);
  }
  grid.sync();

  // ================= P1: conv3 (3x3,32->16,tanh, halo, zero-outside) + conv4 =================
  for (int i = tid; i < 4608; i += 1024) {
    int cin = i / 144, rem = i - cin*144;
    int rr = rem / 12, cc = rem - rr*12;
    int gr = th - 2 + rr, gc = tw - 2 + cc;
    float v = (gr>=0 && gr<64 && gc>=0 && gc<64)
              ? c2buf[(((size_t)b*32 + cin) << 12) + (gr<<6) + gc] : 0.f;
    sm.cv3.c2[cin*168 + rr*14 + cc] = v;
  }
  __syncthreads();
  // conv3 on 10x10 halo; wave wv -> cout wv; lanes 100 px in 2 halves
  for (int half = 0; half < 2; half++) {
    int px = l + (half << 6);
    if (px < 100) {
      int i = px / 10, j = px - i*10;
      int gy = th - 1 + i, gx = tw - 1 + j;
      bool inb = (gy>=0 && gy<64 && gx>=0 && gx<64);
      int co = wv;
      float acc = c3b[co];
      for (int cin = 0; cin < 32; cin++) {
#pragma unroll
        for (int di=0;di<3;di++)
#pragma unroll
          for (int dj=0;dj<3;dj++)
            acc = fmaf(sm.cv3.c2[cin*168 + (i+di)*14 + j+dj],
                       c3w[(co*32+cin)*9 + di*3+dj], acc);
      }
      sm.cv3.c3[co*120 + i*12 + j] = inb ? tanhf(acc) : 0.f;
    }
  }
  __syncthreads();
  if (tid < 64) {
    int py = tid >> 3, px = tid & 7;
    float acc = c4b[0];
    for (int cin = 0; cin < 16; cin++) {
#pragma unroll
      for (int di=0;di<3;di++)
#pragma unroll
        for (int dj=0;dj<3;dj++)
          acc = fmaf(sm.cv3.c3[cin*120 + (py+di)*12 + px+dj], c4w[cin*9 + di*3+dj], acc);
    }
    fbuf[b*NPIX + ((th+py)<<6) + (tw+px)] = acc;
  }
  grid.sync();

  // ================= P2: per-batch sort (blocks 0..3): wave bitonic + merge-path =================
  if (blk < 4) {
    const float* fb = fbuf + (blk << 12);
    unsigned long long key[4];
#pragma unroll
    for (int r=0;r<4;r++) {
      unsigned e = ((unsigned)wv<<8) + ((unsigned)r<<6) + (unsigned)l;
      float v = fb[e];
      unsigned u = __float_as_uint(v);
      u ^= (u >> 31) ? 0xFFFFFFFFu : 0x80000000u;   // order-preserving flip
      key[r] = (((unsigned long long)u) << 32) | e;
    }
    // phase A: sort each contiguous 256-run (one wave) ascending, barrier-free
    for (unsigned k = 2; k <= 256; k <<= 1) {
      for (unsigned j = k >> 1; j > 0; j >>= 1) {
        if (j >= 64) {
          unsigned rj = j >> 6;
#pragma unroll
          for (int r=0;r<4;r++) {
            int pr = r ^ (int)rj;
            if (pr > r) {
              unsigned e = ((unsigned)wv<<8)+((unsigned)r<<6)+(unsigned)l;
              bool up = ((e & k & 255u) == 0);
              unsigned long long a = key[r], c = key[pr];
              bool sw = up ? (c < a) : (c > a);
              if (sw) { key[r] = c; key[pr] = a; }
            }
          }
        } else {
#pragma unroll
          for (int r=0;r<4;r++) {
            unsigned e = ((unsigned)wv<<8)+((unsigned)r<<6)+(unsigned)l;
            unsigned long long a = key[r];
            unsigned long long p = shflx64(a, (int)j);
            bool up = ((e & k & 255u) == 0);
            bool keepmin = ((e & j) == 0) == up;
            key[r] = (keepmin ? (p < a) : (p > a)) ? p : a;
          }
        }
      }
    }
#pragma unroll
    for (int r=0;r<4;r++) sm.srt.A[((unsigned)wv<<8)+((unsigned)r<<6)+l] = key[r];
    __syncthreads();
    // phase B: 4 merge rounds via per-element binary search (distinct keys)
    unsigned long long* src = sm.srt.A;
    unsigned long long* dst = sm.srt.B;
    for (int lg = 8; lg <= 11; lg++) {
      const int L = 1 << lg;
      int p0 = tid << 2;
      int ri = p0 >> lg;
      int base = (ri ^ 1) << lg;
      int mbase = ((ri >> 1) << (lg + 1)) + (p0 & (L - 1));
      unsigned long long kk[4];
      int lo[4], hi[4];
#pragma unroll
      for (int r=0;r<4;r++) { kk[r] = src[p0 + r]; lo[r] = 0; hi[r] = L; }
      for (int s = 0; s <= lg; s++) {
#pragma unroll
        for (int r=0;r<4;r++) {
          if (lo[r] < hi[r]) {
            int mid = (lo[r] + hi[r]) >> 1;
            if (src[base + mid] < kk[r]) lo[r] = mid + 1; else hi[r] = mid;
          }
        }
      }
#pragma unroll
      for (int r=0;r<4;r++) dst[mbase + r + lo[r]] = kk[r];
      __syncthreads();
      unsigned long long* t = src; src = dst; dst = t;
    }
#pragma unroll
    for (int r=0;r<4;r++) {
      int p = (tid << 2) + r;
      unsigned long long kk = src[p];
      unsigned u = (unsigned)(kk >> 32);
      u ^= (u >> 31) ? 0x80000000u : 0xFFFFFFFFu;   // un-flip
      sval[(blk<<12) + p] = __uint_as_float(u);
      sidx[(blk<<12) + p] = (int)(kk & 0xFFFFFFFFu);
    }
  }
  grid.sync();

  // ================= P3: KNN (wave/point, ILP-4) + BN1 moments =================
  {
    int bq = blk >> 6;
    const float* svb = sval + (bq << 12);
    const int*   sib = sidx + (bq << 12);
    const float* fB  = fbuf + (bq << 12);
    double a0=0, a1=0, a2=0, a3=0, a4=0;
    unsigned long long kk[4];
    float fnp[4];
    int   sp[4];
#pragma unroll
    for (int p=0;p<4;p++) {
      int s = ((blk & 63) << 6) + (wv << 2) + p;
      sp[p] = s;
      float fn = svb[s]; fnp[p] = fn;
      int start = s - 32;
      if (start < 0) start = 0;
      if (start > NPIX - 64) start = NPIX - 64;
      int q = start + l;
      float fm = svb[q];
      int   m  = sib[q];
      float sqn = __fmul_rn(fn, fn);
      float pr  = __fmul_rn(fn, fm);
      float dist = __fsub_rn(__fadd_rn(sqn, __fmul_rn(fm, fm)), __fmul_rn(2.0f, pr));
      unsigned u = __float_as_uint(dist);
      u ^= (u >> 31) ? 0xFFFFFFFFu : 0x80000000u;
      kk[p] = (((unsigned long long)u) << 32) | (unsigned)m;
    }
#pragma unroll
    for (int k = 2; k <= 64; k <<= 1)
#pragma unroll
      for (int j = k >> 1; j > 0; j >>= 1) {
#pragma unroll
        for (int p=0;p<4;p++) {
          unsigned long long pp = shflx64(kk[p], j);
          bool up = ((l & k) == 0);
          bool keepmin = ((l & j) == 0) == up;
          kk[p] = (keepmin ? (pp < kk[p]) : (pp > kk[p])) ? pp : kk[p];
        }
      }
#pragma unroll
    for (int p=0;p<4;p++) {
      int mr = (int)(kk[p] & 0xFFFFFFFFu);
      float fn = fnp[p];
      float d = __fsub_rn(fB[mr], fn);       // knn - x1, rank l
      int n = sib[sp[p]];
      if (l >= 1 && l <= 20)
        dw[(size_t)((bq<<12) + n)*KN + (l-1)] = d;
      float dm = (l >= 1 && l <= 20) ? d : 0.f;
      a2 += (double)dm;
      a3 += (double)dm * (double)dm;
      a4 += (double)fn * (double)dm;
      if (l == 0) { a0 += (double)fn; a1 += (double)fn * (double)fn; }
    }
    double v[5] = {a0, a1, a2, a3, a4};
#pragma unroll
    for (int qi=0; qi<5; qi++)
      for (int off=32; off>0; off>>=1) v[qi] += __shfl_down(v[qi], off, 64);
    if (l == 0)
#pragma unroll
      for (int qi=0; qi<5; qi++) sm.kn.sred[wv][qi] = v[qi];
    __syncthreads();
    if (tid == 0) {
      double s0=0, s1=0, s2=0, s3=0, s4=0;
#pragma unroll
      for (int ww=0; ww<16; ww++) {
        s0 += sm.kn.sred[ww][0]; s1 += sm.kn.sred[ww][1]; s2 += sm.kn.sred[ww][2];
        s3 += sm.kn.sred[ww][3]; s4 += sm.kn.sred[ww][4];
      }
      part1[blk*5+0]=s0; part1[blk*5+1]=s1; part1[blk*5+2]=s2;
      part1[blk*5+3]=s3; part1[blk*5+4]=s4;
    }
  }
  grid.sync();

  // ================= P4: BN1 fold (redundant per block, deterministic) + branch =================
  if (tid < 256)
#pragma unroll
    for (int q=0;q<5;q++) sm.f1.red[tid*5+q] = part1[tid*5+q];
  __syncthreads();
  for (int st = 128; st > 0; st >>= 1) {
    if (tid < st)
#pragma unroll
      for (int q=0;q<5;q++) sm.f1.red[tid*5+q] += sm.f1.red[(tid+st)*5+q];
    __syncthreads();
  }
  if (tid < 48) {
    double Ef = sm.f1.red[0]/16384.0, Eff = sm.f1.red[1]/16384.0;
    double Ed = sm.f1.red[2]/MTOT, Edd = sm.f1.red[3]/MTOT, Efd = sm.f1.red[4]/MTOT;
    double Vf = Eff - Ef*Ef, Vd = Edd - Ed*Ed, Cfd = Efd - Ef*Ed;
    int idx = tid;
    double w0 = (double)ew1[idx*2+0], w1 = (double)ew1[idx*2+1];
    double b1 = (double)eb1[idx];
    double m1 = w0*Ef + w1*Ed + b1;
    double v1 = w0*w0*Vf + 2.0*w0*w1*Cfd + w1*w1*Vd;
    double r1 = 1.0 / sqrt(v1 + 1e-5);
    double g = (double)eg1[idx];
    sm.f1.cons[idx*3+0] = (float)(g*r1*w0);
    sm.f1.cons[idx*3+1] = (float)(g*r1*w1);
    sm.f1.cons[idx*3+2] = (float)(g*r1*(b1 - m1) + (double)ebt1[idx]);
  }
  __syncthreads();
  if (wv < 3) {
    int br = wv;
    int row = (blk << 6) + l;
    float sA[16], sB[16], sC[16], sW[16];
#pragma unroll
    for (int c=0;c<16;c++) {
      int idx = br*16 + c;
      sA[c] = sm.f1.cons[idx*3+0];
      sB[c] = sm.f1.cons[idx*3+1];
      sC[c] = sm.f1.cons[idx*3+2];
      sW[c] = ew2[idx];
    }
    float fv = fbuf[row];
    const float* dd = dw + (size_t)row*KN;
    float b2 = eb2[br];
    float P[16];
#pragma unroll
    for (int c=0;c<16;c++) P[c] = fmaf(sA[c], fv, sC[c]);
    float mx = -INFINITY, mn = INFINITY;
    double s = 0.0, s2 = 0.0;
    for (int k=0;k<KN;k++) {
      float d = dd[k];
      float t = b2;
#pragma unroll
      for (int c=0;c<16;c++)
        t = fmaf(sW[c], fmaxf(fmaf(sB[c], d, P[c]), 0.f), t);
      mx = fmaxf(mx, t);
      mn = fminf(mn, t);
      double td = (double)t;
      s += td; s2 += td*td;
    }
    maxo[br*16384 + row] = mx;
    mino[br*16384 + row] = mn;
#pragma unroll
    for (int off=32; off>0; off>>=1) {
      s  += __shfl_down(s, off, 64);
      s2 += __shfl_down(s2, off, 64);
    }
    if (l == 0) {
      part2[(br*256 + blk)*2 + 0] = s;
      part2[(br*256 + blk)*2 + 1] = s2;
    }
  }
  grid.sync();

  // ================= P5: BN2 fold (per block) + pixel shuffle + sigmoid =================
  if (wv < 3) {
    int br = wv;
    double s = 0.0, s2 = 0.0;
#pragma unroll
    for (int t4=0; t4<4; t4++) {
      int bb = l + (t4 << 6);
      s  += part2[(br*256 + bb)*2 + 0];
      s2 += part2[(br*256 + bb)*2 + 1];
    }
#pragma unroll
    for (int off=32; off>0; off>>=1) {
      s  += __shfl_down(s, off, 64);
      s2 += __shfl_down(s2, off, 64);
    }
    if (l == 0) {
      double mean = s / MTOT;
      double var = s2 / MTOT - mean*mean;
      double r2 = 1.0 / sqrt(var + 1e-5);
      double sc = (double)eg2[br] * r2;
      sm.ot.c2c[br][0] = sc;
      sm.ot.c2c[br][1] = (double)ebt2[br] - sc*mean;
    }
  }
  __syncthreads();
  if (tid < 256) {
    int tg = (blk << 8) + tid;     // 65536
    int bo = tg >> 14;
    int y = (tg >> 7) & 127, xx = tg & 127;
    int n = ((y>>1)<<6) + (xx>>1);
    int ch = ((y&1)<<1) + (xx&1);
    float v;
    if (ch == 0) {
      v = fbuf[bo*NPIX + n];
    } else {
      int br = ch - 1;
      float sc = (float)sm.ot.c2c[br][0], sh = (float)sm.ot.c2c[br][1];
      float base = (sc >= 0.f) ? maxo[br*16384 + bo*NPIX + n]
                               : mino[br*16384 + bo*NPIX + n];
      v = fmaxf(fmaf(sc, base, sh), 0.f);
    }
    out[tg] = 1.f / (1.f + expf(-v));
  }
}

extern "C" void kernel_launch(void* const* d_in, const int* in_sizes, int n_in,
                              void* d_out, int out_size, void* d_ws, size_t ws_size,
                              hipStream_t stream) {
  (void)in_sizes; (void)n_in; (void)out_size; (void)ws_size;
  const float* x    = (const float*)d_in[0];
  const float* c1w  = (const float*)d_in[1];
  const float* c1b  = (const float*)d_in[2];
  const float* c2w  = (const float*)d_in[3];
  const float* c2b  = (const float*)d_in[4];
  const float* c3w  = (const float*)d_in[5];
  const float* c3b  = (const float*)d_in[6];
  const float* c4w  = (const float*)d_in[7];
  const float* c4b  = (const float*)d_in[8];
  const float* ew1  = (const float*)d_in[9];
  const float* eb1  = (const float*)d_in[10];
  const float* eg1  = (const float*)d_in[11];
  const float* ebt1 = (const float*)d_in[12];
  const float* ew2  = (const float*)d_in[13];
  const float* eb2  = (const float*)d_in[14];
  const float* eg2  = (const float*)d_in[15];
  const float* ebt2 = (const float*)d_in[16];
  float* out = (float*)d_out;
  float* ws  = (float*)d_ws;

  void* args[] = {
    (void*)&x, (void*)&c1w, (void*)&c1b, (void*)&c2w, (void*)&c2b,
    (void*)&c3w, (void*)&c3b, (void*)&c4w, (void*)&c4b,
    (void*)&ew1, (void*)&eb1, (void*)&eg1, (void*)&ebt1,
    (void*)&ew2, (void*)&eb2, (void*)&eg2, (void*)&ebt2,
    (void*)&out, (void*)&ws
  };
  hipLaunchCooperativeKernel((void*)mega_k, dim3(256), dim3(1024), args, 0, stream);
}

// Round 10
// 138.399 us; speedup vs baseline: 2.7065x; 1.9276x over previous
//
#include <hip/hip_runtime.h>
#include <math.h>

#define NPIX 4096
#define KN 20
#define MTOT 327680.0    // B*N*K

__device__ inline unsigned long long shflx64(unsigned long long v, int m) {
  unsigned lo = (unsigned)v, hi = (unsigned)(v >> 32);
  lo = __shfl_xor(lo, m, 64);
  hi = __shfl_xor(hi, m, 64);
  return (((unsigned long long)hi) << 32) | lo;
}

// ================= K1: conv1 (5x5,1->64,tanh, zero-outside halo) + conv2 (3x3,64->32,tanh) =================
__global__ __launch_bounds__(512) void conv12_k(const float* __restrict__ x,
    const float* __restrict__ c1w, const float* __restrict__ c1b,
    const float* __restrict__ c2w, const float* __restrict__ c2b,
    float* __restrict__ c2buf) {
  __shared__ float sx[224];          // 14x14 halo, stride 16
  __shared__ float sc1[7680];        // 64 x 10x10, stride 12
  const int tid = threadIdx.x;
  const int l = tid & 63, w = tid >> 6;       // 8 waves
  const int b = blockIdx.x, tile = blockIdx.y;
  const int th = (tile >> 3) << 3, tw = (tile & 7) << 3;

  for (int i = tid; i < 196; i += 512) {
    int r = i / 14, c = i - r*14;
    int gr = th - 3 + r, gc = tw - 3 + c;
    sx[r*16 + c] = (gr>=0 && gr<64 && gc>=0 && gc<64) ? x[b*NPIX + (gr<<6) + gc] : 0.f;
  }
  __syncthreads();
  // conv1 on 10x10 halo; wave w -> couts w*8..+7
  for (int half = 0; half < 2; half++) {
    int px = l + (half << 6);
    if (px < 100) {
      int i = px / 10, j = px - i*10;
      int gy = th - 1 + i, gx = tw - 1 + j;
      bool inb = (gy>=0 && gy<64 && gx>=0 && gx<64);
      for (int cc = 0; cc < 8; cc++) {
        int co = (w << 3) + cc;
        float acc = c1b[co];
#pragma unroll
        for (int di=0; di<5; di++)
#pragma unroll
          for (int dj=0; dj<5; dj++)
            acc = fmaf(sx[(i+di)*16 + j+dj], c1w[co*25 + di*5 + dj], acc);
        sc1[co*120 + i*12 + j] = inb ? tanhf(acc) : 0.f;
      }
    }
  }
  __syncthreads();
  // conv2 exact 8x8: px = tid&63, group g = tid>>6 -> couts g*4..+3
  {
    int py = l >> 3, px2 = l & 7;
    int co0 = w << 2;
    float acc[4];
#pragma unroll
    for (int o=0;o<4;o++) acc[o] = c2b[co0 + o];
    for (int cin = 0; cin < 64; cin++) {
      float v[9];
#pragma unroll
      for (int di=0;di<3;di++)
#pragma unroll
        for (int dj=0;dj<3;dj++)
          v[di*3+dj] = sc1[cin*120 + (py+di)*12 + px2+dj];
      const float* wc = c2w + ((co0*64) + cin)*9;
#pragma unroll
      for (int o=0;o<4;o++)
#pragma unroll
        for (int t=0;t<9;t++)
          acc[o] = fmaf(v[t], wc[o*576 + t], acc[o]);
    }
#pragma unroll
    for (int o=0;o<4;o++)
      c2buf[(((size_t)b*32 + co0 + o) << 12) + ((th+py)<<6) + (tw+px2)] = tanhf(acc[o]);
  }
}

// ================= K2: conv3 (3x3,32->16,tanh, zero-outside halo) + conv4 (3x3,16->1) =================
__global__ __launch_bounds__(512) void conv34_k(const float* __restrict__ c2buf,
    const float* __restrict__ c3w, const float* __restrict__ c3b,
    const float* __restrict__ c4w, const float* __restrict__ c4b,
    float* __restrict__ fbuf) {
  __shared__ float sc2[5376];        // 32 x 12x12, stride 14
  __shared__ float sc3[1920];        // 16 x 10x10, stride 12
  const int tid = threadIdx.x;
  const int l = tid & 63, w = tid >> 6;
  const int b = blockIdx.x, tile = blockIdx.y;
  const int th = (tile >> 3) << 3, tw = (tile & 7) << 3;

  for (int i = tid; i < 4608; i += 512) {
    int cin = i / 144, rem = i - cin*144;
    int rr = rem / 12, cc = rem - rr*12;
    int gr = th - 2 + rr, gc = tw - 2 + cc;
    float v = (gr>=0 && gr<64 && gc>=0 && gc<64)
              ? c2buf[(((size_t)b*32 + cin) << 12) + (gr<<6) + gc] : 0.f;
    sc2[cin*168 + rr*14 + cc] = v;
  }
  __syncthreads();
  // conv3 on 10x10 halo; wave w -> couts w*2..+1
  for (int half = 0; half < 2; half++) {
    int px = l + (half << 6);
    if (px < 100) {
      int i = px / 10, j = px - i*10;
      int gy = th - 1 + i, gx = tw - 1 + j;
      bool inb = (gy>=0 && gy<64 && gx>=0 && gx<64);
      for (int cc = 0; cc < 2; cc++) {
        int co = (w << 1) + cc;
        float acc = c3b[co];
        for (int cin = 0; cin < 32; cin++) {
#pragma unroll
          for (int di=0;di<3;di++)
#pragma unroll
            for (int dj=0;dj<3;dj++)
              acc = fmaf(sc2[cin*168 + (i+di)*14 + j+dj],
                         c3w[(co*32+cin)*9 + di*3+dj], acc);
        }
        sc3[co*120 + i*12 + j] = inb ? tanhf(acc) : 0.f;
      }
    }
  }
  __syncthreads();
  if (tid < 64) {
    int py = tid >> 3, px = tid & 7;
    float acc = c4b[0];
    for (int cin = 0; cin < 16; cin++) {
#pragma unroll
      for (int di=0;di<3;di++)
#pragma unroll
        for (int dj=0;dj<3;dj++)
          acc = fmaf(sc3[cin*120 + (py+di)*12 + px+dj], c4w[cin*9 + di*3+dj], acc);
    }
    fbuf[b*NPIX + ((th+py)<<6) + (tw+px)] = acc;
  }
}

// ================= K3: per-batch sort: wave bitonic (256-runs) + merge-path =================
__global__ __launch_bounds__(1024) void sort2_k(const float* __restrict__ f,
    float* __restrict__ sval, int* __restrict__ sidx) {
  int b = blockIdx.x;
  int tid = threadIdx.x;
  int l = tid & 63, w = tid >> 6;
  __shared__ unsigned long long Ab[NPIX];
  __shared__ unsigned long long Bb[NPIX];
  const float* fb = f + b*NPIX;
  unsigned long long key[4];
#pragma unroll
  for (int r=0;r<4;r++) {
    unsigned e = (w<<8) + (r<<6) + l;
    float v = fb[e];
    unsigned u = __float_as_uint(v);
    u ^= (u >> 31) ? 0xFFFFFFFFu : 0x80000000u;   // order-preserving flip
    key[r] = (((unsigned long long)u) << 32) | e;
  }
  for (unsigned k = 2; k <= 256; k <<= 1) {
    for (unsigned j = k >> 1; j > 0; j >>= 1) {
      if (j >= 64) {
        unsigned rj = j >> 6;
#pragma unroll
        for (int r=0;r<4;r++) {
          int pr = r ^ (int)rj;
          if (pr > r) {
            unsigned e = (w<<8)+((unsigned)r<<6)+l;
            bool up = ((e & k & 255u) == 0);
            unsigned long long a = key[r], c = key[pr];
            bool sw = up ? (c < a) : (c > a);
            if (sw) { key[r] = c; key[pr] = a; }
          }
        }
      } else {
#pragma unroll
        for (int r=0;r<4;r++) {
          unsigned e = (w<<8)+((unsigned)r<<6)+l;
          unsigned long long a = key[r];
          unsigned long long p = shflx64(a, (int)j);
          bool up = ((e & k & 255u) == 0);
          bool keepmin = ((e & j) == 0) == up;
          key[r] = (keepmin ? (p < a) : (p > a)) ? p : a;
        }
      }
    }
  }
#pragma unroll
  for (int r=0;r<4;r++) Ab[(w<<8)+(r<<6)+l] = key[r];
  __syncthreads();
  unsigned long long* src = Ab;
  unsigned long long* dst = Bb;
  for (int lg = 8; lg <= 11; lg++) {
    const int L = 1 << lg;
    int p0 = tid << 2;
    int ri = p0 >> lg;
    int base = (ri ^ 1) << lg;
    int mbase = ((ri >> 1) << (lg + 1)) + (p0 & (L - 1));
    unsigned long long kk[4];
    int lo[4], hi[4];
#pragma unroll
    for (int r=0;r<4;r++) { kk[r] = src[p0 + r]; lo[r] = 0; hi[r] = L; }
    for (int s = 0; s <= lg; s++) {
#pragma unroll
      for (int r=0;r<4;r++) {
        if (lo[r] < hi[r]) {
          int mid = (lo[r] + hi[r]) >> 1;
          if (src[base + mid] < kk[r]) lo[r] = mid + 1; else hi[r] = mid;
        }
      }
    }
#pragma unroll
    for (int r=0;r<4;r++) dst[mbase + r + lo[r]] = kk[r];
    __syncthreads();
    unsigned long long* t = src; src = dst; dst = t;
  }
#pragma unroll
  for (int r=0;r<4;r++) {
    int p = (tid << 2) + r;
    unsigned long long kk = src[p];
    unsigned u = (unsigned)(kk >> 32);
    u ^= (u >> 31) ? 0x80000000u : 0xFFFFFFFFu;   // un-flip
    sval[b*NPIX + p] = __uint_as_float(u);
    sidx[b*NPIX + p] = (int)(kk & 0xFFFFFFFFu);
  }
}

// ================= K4: KNN (wave/point ILP-4) + BN1 moment partials =================
__global__ __launch_bounds__(512) void knn4_k(const float* __restrict__ f,
    const float* __restrict__ sval, const int* __restrict__ sidx,
    float* __restrict__ dout, double* __restrict__ part1) {
  const int tid = threadIdx.x, blk = blockIdx.x;   // 512 blocks
  const int l = tid & 63, w = tid >> 6;            // 8 waves
  const int bq = blk >> 7;                          // 128 blocks per batch
  const float* svb = sval + (bq << 12);
  const int*   sib = sidx + (bq << 12);
  const float* fB  = f + (bq << 12);
  double a0=0, a1=0, a2=0, a3=0, a4=0;
  unsigned long long kk[4];
  float fnp[4];
  int   sp[4];
#pragma unroll
  for (int p=0;p<4;p++) {
    int s = ((blk & 127) << 5) + (w << 2) + p;
    sp[p] = s;
    float fn = svb[s]; fnp[p] = fn;
    int start = s - 32;
    if (start < 0) start = 0;
    if (start > NPIX - 64) start = NPIX - 64;
    int q = start + l;
    float fm = svb[q];
    int   m  = sib[q];
    float sqn = __fmul_rn(fn, fn);
    float pr  = __fmul_rn(fn, fm);
    float dist = __fsub_rn(__fadd_rn(sqn, __fmul_rn(fm, fm)), __fmul_rn(2.0f, pr));
    unsigned u = __float_as_uint(dist);
    u ^= (u >> 31) ? 0xFFFFFFFFu : 0x80000000u;
    kk[p] = (((unsigned long long)u) << 32) | (unsigned)m;
  }
#pragma unroll
  for (int k = 2; k <= 64; k <<= 1)
#pragma unroll
    for (int j = k >> 1; j > 0; j >>= 1) {
#pragma unroll
      for (int p=0;p<4;p++) {
        unsigned long long pp = shflx64(kk[p], j);
        bool up = ((l & k) == 0);
        bool keepmin = ((l & j) == 0) == up;
        kk[p] = (keepmin ? (pp < kk[p]) : (pp > kk[p])) ? pp : kk[p];
      }
    }
#pragma unroll
  for (int p=0;p<4;p++) {
    int mr = (int)(kk[p] & 0xFFFFFFFFu);
    float fn = fnp[p];
    float d = __fsub_rn(fB[mr], fn);       // knn - x1, rank l
    int n = sib[sp[p]];
    if (l >= 1 && l <= 20)
      dout[(size_t)((bq<<12) + n)*KN + (l-1)] = d;
    float dm = (l >= 1 && l <= 20) ? d : 0.f;
    a2 += (double)dm;
    a3 += (double)dm * (double)dm;
    a4 += (double)fn * (double)dm;
    if (l == 0) { a0 += (double)fn; a1 += (double)fn * (double)fn; }
  }
  double v[5] = {a0, a1, a2, a3, a4};
#pragma unroll
  for (int qi=0; qi<5; qi++)
    for (int off=32; off>0; off>>=1) v[qi] += __shfl_down(v[qi], off, 64);
  __shared__ double sred[8][5];
  if (l == 0)
#pragma unroll
    for (int qi=0; qi<5; qi++) sred[w][qi] = v[qi];
  __syncthreads();
  if (tid == 0) {
#pragma unroll
    for (int qi=0; qi<5; qi++) {
      double s = 0.0;
#pragma unroll
      for (int ww=0; ww<8; ww++) s += sred[ww][qi];
      part1[blk*5 + qi] = s;
    }
  }
}

// ================= K5: redundant BN1 fold + per-branch o_pre max/min + BN2 partials =================
__global__ __launch_bounds__(64) void branch_k(const float* __restrict__ f,
    const float* __restrict__ dw, const double* __restrict__ part1,
    const float* __restrict__ ew1, const float* __restrict__ eb1,
    const float* __restrict__ eg1, const float* __restrict__ ebt1,
    const float* __restrict__ ew2, const float* __restrict__ eb2,
    float* __restrict__ maxo, float* __restrict__ mino,
    double* __restrict__ part2) {
  const int l = threadIdx.x;
  const int blk = blockIdx.x, br = blockIdx.y;
  // redundant, deterministic BN1 fold (identical in every block)
  double a[5] = {0,0,0,0,0};
  for (int b2 = l; b2 < 512; b2 += 64)
#pragma unroll
    for (int q=0;q<5;q++) a[q] += part1[b2*5+q];
#pragma unroll
  for (int q=0;q<5;q++)
    for (int off=32; off>0; off>>=1) a[q] += __shfl_down(a[q], off, 64);
#pragma unroll
  for (int q=0;q<5;q++) a[q] = __shfl(a[q], 0, 64);
  double Ef = a[0]/16384.0, Eff = a[1]/16384.0;
  double Ed = a[2]/MTOT, Edd = a[3]/MTOT, Efd = a[4]/MTOT;
  double Vf = Eff - Ef*Ef, Vd = Edd - Ed*Ed, Cfd = Efd - Ef*Ed;
  float sA[16], sB[16], sC[16], sW[16];
#pragma unroll
  for (int c=0;c<16;c++) {
    int idx = br*16 + c;
    double w0 = (double)ew1[idx*2+0], w1 = (double)ew1[idx*2+1];
    double b1 = (double)eb1[idx];
    double m1 = w0*Ef + w1*Ed + b1;
    double v1 = w0*w0*Vf + 2.0*w0*w1*Cfd + w1*w1*Vd;
    double r1 = 1.0 / sqrt(v1 + 1e-5);
    double g = (double)eg1[idx];
    sA[c] = (float)(g*r1*w0);
    sB[c] = (float)(g*r1*w1);
    sC[c] = (float)(g*r1*(b1 - m1) + (double)ebt1[idx]);
    sW[c] = ew2[idx];
  }
  int row = (blk << 6) + l;
  float fv = f[row];
  const float* dd = dw + (size_t)row*KN;
  float b2v = eb2[br];
  float P[16];
#pragma unroll
  for (int c=0;c<16;c++) P[c] = fmaf(sA[c], fv, sC[c]);
  float mx = -INFINITY, mn = INFINITY;
  double s = 0.0, s2 = 0.0;
  for (int k=0;k<KN;k++) {
    float d = dd[k];
    float t = b2v;
#pragma unroll
    for (int c=0;c<16;c++)
      t = fmaf(sW[c], fmaxf(fmaf(sB[c], d, P[c]), 0.f), t);
    mx = fmaxf(mx, t);
    mn = fminf(mn, t);
    double td = (double)t;
    s += td; s2 += td*td;
  }
  maxo[br*16384 + row] = mx;
  mino[br*16384 + row] = mn;
#pragma unroll
  for (int off=32; off>0; off>>=1) {
    s  += __shfl_down(s, off, 64);
    s2 += __shfl_down(s2, off, 64);
  }
  if (l == 0) {
    part2[(br*256 + blk)*2 + 0] = s;
    part2[(br*256 + blk)*2 + 1] = s2;
  }
}

// ================= K6: redundant BN2 fold + pixel shuffle + sigmoid =================
__global__ __launch_bounds__(256) void out_k(const float* __restrict__ f,
    const float* __restrict__ maxo, const float* __restrict__ mino,
    const double* __restrict__ part2,
    const float* __restrict__ eg2, const float* __restrict__ ebt2,
    float* __restrict__ out) {
  __shared__ float c2c[3][2];
  const int tid = threadIdx.x, blk = blockIdx.x;
  const int l = tid & 63, w = tid >> 6;
  if (w < 3) {
    int br = w;
    double s = 0.0, s2 = 0.0;
#pragma unroll
    for (int i=0;i<4;i++) {
      int bb = l + (i << 6);
      s  += part2[(br*256 + bb)*2 + 0];
      s2 += part2[(br*256 + bb)*2 + 1];
    }
#pragma unroll
    for (int off=32; off>0; off>>=1) {
      s  += __shfl_down(s, off, 64);
      s2 += __shfl_down(s2, off, 64);
    }
    if (l == 0) {
      double mean = s / MTOT;
      double var = s2 / MTOT - mean*mean;
      double r2 = 1.0 / sqrt(var + 1e-5);
      double sc = (double)eg2[br] * r2;
      c2c[br][0] = (float)sc;
      c2c[br][1] = (float)((double)ebt2[br] - sc*mean);
    }
  }
  __syncthreads();
  int tg = (blk << 8) + tid;     // 65536
  int bo = tg >> 14;
  int y = (tg >> 7) & 127, xx = tg & 127;
  int n = ((y>>1)<<6) + (xx>>1);
  int ch = ((y&1)<<1) + (xx&1);
  float v;
  if (ch == 0) {
    v = f[bo*NPIX + n];
  } else {
    int br = ch - 1;
    float sc = c2c[br][0], sh = c2c[br][1];
    float base = (sc >= 0.f) ? maxo[br*16384 + bo*NPIX + n]
                             : mino[br*16384 + bo*NPIX + n];
    v = fmaxf(fmaf(sc, base, sh), 0.f);
  }
  out[tg] = 1.f / (1.f + expf(-v));
}

extern "C" void kernel_launch(void* const* d_in, const int* in_sizes, int n_in,
                              void* d_out, int out_size, void* d_ws, size_t ws_size,
                              hipStream_t stream) {
  (void)in_sizes; (void)n_in; (void)out_size; (void)ws_size;
  const float* x    = (const float*)d_in[0];
  const float* c1w  = (const float*)d_in[1];
  const float* c1b  = (const float*)d_in[2];
  const float* c2w  = (const float*)d_in[3];
  const float* c2b  = (const float*)d_in[4];
  const float* c3w  = (const float*)d_in[5];
  const float* c3b  = (const float*)d_in[6];
  const float* c4w  = (const float*)d_in[7];
  const float* c4b  = (const float*)d_in[8];
  const float* ew1  = (const float*)d_in[9];
  const float* eb1  = (const float*)d_in[10];
  const float* eg1  = (const float*)d_in[11];
  const float* ebt1 = (const float*)d_in[12];
  const float* ew2  = (const float*)d_in[13];
  const float* eb2  = (const float*)d_in[14];
  const float* eg2  = (const float*)d_in[15];
  const float* ebt2 = (const float*)d_in[16];
  float* out = (float*)d_out;
  float* ws  = (float*)d_ws;

  float*  c2buf = ws;                       // 524288 floats
  float*  fbuf  = ws + 524288;              // 16384
  float*  dw    = ws + 540672;              // 327680
  float*  sval  = ws + 868352;              // 16384
  int*    sidx  = (int*)(ws + 884736);      // 16384
  float*  maxo  = ws + 901120;              // 49152
  float*  mino  = ws + 950272;              // 49152
  double* part1 = (double*)(ws + 999424);   // 512*5 doubles
  double* part2 = (double*)(ws + 1004544);  // 256*3*2 doubles

  conv12_k<<<dim3(4,64), 512, 0, stream>>>(x, c1w, c1b, c2w, c2b, c2buf);
  conv34_k<<<dim3(4,64), 512, 0, stream>>>(c2buf, c3w, c3b, c4w, c4b, fbuf);
  sort2_k<<<4, 1024, 0, stream>>>(fbuf, sval, sidx);
  knn4_k<<<512, 512, 0, stream>>>(fbuf, sval, sidx, dw, part1);
  branch_k<<<dim3(256,3), 64, 0, stream>>>(fbuf, dw, part1,
      ew1, eb1, eg1, ebt1, ew2, eb2, maxo, mino, part2);
  out_k<<<256, 256, 0, stream>>>(fbuf, maxo, mino, part2, eg2, ebt2, out);
}

// Round 11
// 138.024 us; speedup vs baseline: 2.7138x; 1.0027x over previous
//
#include <hip/hip_runtime.h>
#include <math.h>

#define NPIX 4096
#define KN 20
#define MTOT 327680.0    // B*N*K

__device__ inline unsigned long long shflx64(unsigned long long v, int m) {
  unsigned lo = (unsigned)v, hi = (unsigned)(v >> 32);
  lo = __shfl_xor(lo, m, 64);
  hi = __shfl_xor(hi, m, 64);
  return (((unsigned long long)hi) << 32) | lo;
}

// ===== K1: conv1 (5x5,1->64,tanh, zero-outside) + conv2 (3x3,64->32,tanh) =====
// 4x16 row-strip per block, conv2 couts z-split 16/16. Wave-uniform weights.
__global__ __launch_bounds__(512) void conv12_k(const float* __restrict__ x,
    const float* __restrict__ c1w, const float* __restrict__ c1b,
    const float* __restrict__ c2w, const float* __restrict__ c2b,
    float* __restrict__ c2buf) {
  __shared__ float sx[230];          // 10 x 22, stride 23
  __shared__ float sc1[64*114];      // 64 ch x 6 x 18, stride 19 (29.2KB)
  const int tid = threadIdx.x;
  const int l = tid & 63, w = tid >> 6;       // 8 waves
  const int b = blockIdx.x, st = blockIdx.y, z = blockIdx.z;
  const int th = (st >> 2) << 2, tw = (st & 3) << 4;

  for (int i = tid; i < 220; i += 512) {
    int r = i / 22, c = i - r*22;
    int gr = th - 3 + r, gc = tw - 3 + c;
    sx[r*23 + c] = (gr>=0 && gr<64 && gc>=0 && gc<64) ? x[b*NPIX + (gr<<6) + gc] : 0.f;
  }
  __syncthreads();
  // conv1 on 6x18 halo region; wave w -> couts w*8..+7 (uniform)
  for (int half = 0; half < 2; half++) {
    int px = l + (half << 6);
    if (px < 108) {
      int i = px / 18, j = px - i*18;
      int gy = th - 1 + i, gx = tw - 1 + j;
      bool inb = (gy>=0 && gy<64 && gx>=0 && gx<64);
      for (int cc = 0; cc < 8; cc++) {
        int co = (w << 3) + cc;
        float acc = c1b[co];
#pragma unroll
        for (int di=0; di<5; di++)
#pragma unroll
          for (int dj=0; dj<5; dj++)
            acc = fmaf(sx[(i+di)*23 + j+dj], c1w[co*25 + di*5 + dj], acc);
        sc1[co*114 + i*19 + j] = inb ? tanhf(acc) : 0.f;
      }
    }
  }
  __syncthreads();
  // conv2 exact 4x16: lane -> pixel; couts co0 = z*16 + w*2 (wave-uniform)
  {
    int py = l >> 4, px2 = l & 15;
    int co0 = (z << 4) + (w << 1);
    float acc[2];
#pragma unroll
    for (int o=0;o<2;o++) acc[o] = c2b[co0 + o];
    for (int cin = 0; cin < 64; cin++) {
      float v[9];
#pragma unroll
      for (int di=0;di<3;di++)
#pragma unroll
        for (int dj=0;dj<3;dj++)
          v[di*3+dj] = sc1[cin*114 + (py+di)*19 + px2+dj];
      const float* wc = c2w + ((co0*64) + cin)*9;
#pragma unroll
      for (int o=0;o<2;o++)
#pragma unroll
        for (int t=0;t<9;t++)
          acc[o] = fmaf(v[t], wc[o*576 + t], acc[o]);
    }
#pragma unroll
    for (int o=0;o<2;o++)
      c2buf[(((size_t)b*32 + co0 + o) << 12) + ((th+py)<<6) + (tw+px2)] = tanhf(acc[o]);
  }
}

// ===== K2: conv3 (3x3,32->16,tanh, zero-outside) + conv4 (3x3,16->1) =====
// 4x8 subtile per block (512 blocks). Wave-uniform conv3 couts.
__global__ __launch_bounds__(512) void conv34_k(const float* __restrict__ c2buf,
    const float* __restrict__ c3w, const float* __restrict__ c3b,
    const float* __restrict__ c4w, const float* __restrict__ c4b,
    float* __restrict__ fbuf) {
  __shared__ float sc2[32*104];      // 32 ch x 8 x 12, stride 13 (13.3KB)
  __shared__ float sc3[16*78];       // 16 ch x 6 x 10, stride 13
  const int tid = threadIdx.x;
  const int l = tid & 63, w = tid >> 6;
  const int b = blockIdx.x, st = blockIdx.y;
  const int th = (st >> 3) << 2, tw = (st & 7) << 3;

  for (int i = tid; i < 32*96; i += 512) {
    int cin = i / 96, rem = i - cin*96;
    int rr = rem / 12, cc = rem - rr*12;
    int gr = th - 2 + rr, gc = tw - 2 + cc;
    float v = (gr>=0 && gr<64 && gc>=0 && gc<64)
              ? c2buf[(((size_t)b*32 + cin) << 12) + (gr<<6) + gc] : 0.f;
    sc2[cin*104 + rr*13 + cc] = v;
  }
  __syncthreads();
  // conv3 on 6x10 halo; wave w -> couts w*2..+1 (uniform)
  if (l < 60) {
    int i = l / 10, j = l - i*10;
    int gy = th - 1 + i, gx = tw - 1 + j;
    bool inb = (gy>=0 && gy<64 && gx>=0 && gx<64);
    for (int cc = 0; cc < 2; cc++) {
      int co = (w << 1) + cc;
      float acc = c3b[co];
      for (int cin = 0; cin < 32; cin++) {
#pragma unroll
        for (int di=0;di<3;di++)
#pragma unroll
          for (int dj=0;dj<3;dj++)
            acc = fmaf(sc2[cin*104 + (i+di)*13 + j+dj],
                       c3w[(co*32+cin)*9 + di*3+dj], acc);
      }
      sc3[co*78 + i*13 + j] = inb ? tanhf(acc) : 0.f;
    }
  }
  __syncthreads();
  if (tid < 32) {
    int py = tid >> 3, px = tid & 7;
    float acc = c4b[0];
    for (int cin = 0; cin < 16; cin++) {
#pragma unroll
      for (int di=0;di<3;di++)
#pragma unroll
        for (int dj=0;dj<3;dj++)
          acc = fmaf(sc3[cin*78 + (py+di)*13 + px+dj], c4w[cin*9 + di*3+dj], acc);
    }
    fbuf[b*NPIX + ((th+py)<<6) + (tw+px)] = acc;
  }
}

// ===== K3: per-batch sort: wave bitonic (256-runs) + merge-path =====
__global__ __launch_bounds__(1024) void sort2_k(const float* __restrict__ f,
    float* __restrict__ sval, int* __restrict__ sidx) {
  int b = blockIdx.x;
  int tid = threadIdx.x;
  int l = tid & 63, w = tid >> 6;
  __shared__ unsigned long long Ab[NPIX];
  __shared__ unsigned long long Bb[NPIX];
  const float* fb = f + b*NPIX;
  unsigned long long key[4];
#pragma unroll
  for (int r=0;r<4;r++) {
    unsigned e = (w<<8) + (r<<6) + l;
    float v = fb[e];
    unsigned u = __float_as_uint(v);
    u ^= (u >> 31) ? 0xFFFFFFFFu : 0x80000000u;   // order-preserving flip
    key[r] = (((unsigned long long)u) << 32) | e;
  }
  for (unsigned k = 2; k <= 256; k <<= 1) {
    for (unsigned j = k >> 1; j > 0; j >>= 1) {
      if (j >= 64) {
        unsigned rj = j >> 6;
#pragma unroll
        for (int r=0;r<4;r++) {
          int pr = r ^ (int)rj;
          if (pr > r) {
            unsigned e = (w<<8)+((unsigned)r<<6)+l;
            bool up = ((e & k & 255u) == 0);
            unsigned long long a = key[r], c = key[pr];
            bool sw = up ? (c < a) : (c > a);
            if (sw) { key[r] = c; key[pr] = a; }
          }
        }
      } else {
#pragma unroll
        for (int r=0;r<4;r++) {
          unsigned e = (w<<8)+((unsigned)r<<6)+l;
          unsigned long long a = key[r];
          unsigned long long p = shflx64(a, (int)j);
          bool up = ((e & k & 255u) == 0);
          bool keepmin = ((e & j) == 0) == up;
          key[r] = (keepmin ? (p < a) : (p > a)) ? p : a;
        }
      }
    }
  }
#pragma unroll
  for (int r=0;r<4;r++) Ab[(w<<8)+(r<<6)+l] = key[r];
  __syncthreads();
  unsigned long long* src = Ab;
  unsigned long long* dst = Bb;
  for (int lg = 8; lg <= 11; lg++) {
    const int L = 1 << lg;
    int p0 = tid << 2;
    int ri = p0 >> lg;
    int base = (ri ^ 1) << lg;
    int mbase = ((ri >> 1) << (lg + 1)) + (p0 & (L - 1));
    unsigned long long kk[4];
    int lo[4], hi[4];
#pragma unroll
    for (int r=0;r<4;r++) { kk[r] = src[p0 + r]; lo[r] = 0; hi[r] = L; }
    for (int s = 0; s <= lg; s++) {
#pragma unroll
      for (int r=0;r<4;r++) {
        if (lo[r] < hi[r]) {
          int mid = (lo[r] + hi[r]) >> 1;
          if (src[base + mid] < kk[r]) lo[r] = mid + 1; else hi[r] = mid;
        }
      }
    }
#pragma unroll
    for (int r=0;r<4;r++) dst[mbase + r + lo[r]] = kk[r];
    __syncthreads();
    unsigned long long* t = src; src = dst; dst = t;
  }
#pragma unroll
  for (int r=0;r<4;r++) {
    int p = (tid << 2) + r;
    unsigned long long kk = src[p];
    unsigned u = (unsigned)(kk >> 32);
    u ^= (u >> 31) ? 0x80000000u : 0xFFFFFFFFu;   // un-flip
    sval[b*NPIX + p] = __uint_as_float(u);
    sidx[b*NPIX + p] = (int)(kk & 0xFFFFFFFFu);
  }
}

// ===== K4: KNN (wave/point ILP-4) + BN1 moment partials =====
__global__ __launch_bounds__(512) void knn4_k(const float* __restrict__ f,
    const float* __restrict__ sval, const int* __restrict__ sidx,
    float* __restrict__ dout, double* __restrict__ part1) {
  const int tid = threadIdx.x, blk = blockIdx.x;   // 512 blocks
  const int l = tid & 63, w = tid >> 6;            // 8 waves
  const int bq = blk >> 7;                          // 128 blocks per batch
  const float* svb = sval + (bq << 12);
  const int*   sib = sidx + (bq << 12);
  const float* fB  = f + (bq << 12);
  double a0=0, a1=0, a2=0, a3=0, a4=0;
  unsigned long long kk[4];
  float fnp[4];
  int   sp[4];
#pragma unroll
  for (int p=0;p<4;p++) {
    int s = ((blk & 127) << 5) + (w << 2) + p;
    sp[p] = s;
    float fn = svb[s]; fnp[p] = fn;
    int start = s - 32;
    if (start < 0) start = 0;
    if (start > NPIX - 64) start = NPIX - 64;
    int q = start + l;
    float fm = svb[q];
    int   m  = sib[q];
    float sqn = __fmul_rn(fn, fn);
    float pr  = __fmul_rn(fn, fm);
    float dist = __fsub_rn(__fadd_rn(sqn, __fmul_rn(fm, fm)), __fmul_rn(2.0f, pr));
    unsigned u = __float_as_uint(dist);
    u ^= (u >> 31) ? 0xFFFFFFFFu : 0x80000000u;
    kk[p] = (((unsigned long long)u) << 32) | (unsigned)m;
  }
#pragma unroll
  for (int k = 2; k <= 64; k <<= 1)
#pragma unroll
    for (int j = k >> 1; j > 0; j >>= 1) {
#pragma unroll
      for (int p=0;p<4;p++) {
        unsigned long long pp = shflx64(kk[p], j);
        bool up = ((l & k) == 0);
        bool keepmin = ((l & j) == 0) == up;
        kk[p] = (keepmin ? (pp < kk[p]) : (pp > kk[p])) ? pp : kk[p];
      }
    }
#pragma unroll
  for (int p=0;p<4;p++) {
    int mr = (int)(kk[p] & 0xFFFFFFFFu);
    float fn = fnp[p];
    float d = __fsub_rn(fB[mr], fn);       // knn - x1, rank l
    int n = sib[sp[p]];
    if (l >= 1 && l <= 20)
      dout[(size_t)((bq<<12) + n)*KN + (l-1)] = d;
    float dm = (l >= 1 && l <= 20) ? d : 0.f;
    a2 += (double)dm;
    a3 += (double)dm * (double)dm;
    a4 += (double)fn * (double)dm;
    if (l == 0) { a0 += (double)fn; a1 += (double)fn * (double)fn; }
  }
  double v[5] = {a0, a1, a2, a3, a4};
#pragma unroll
  for (int qi=0; qi<5; qi++)
    for (int off=32; off>0; off>>=1) v[qi] += __shfl_down(v[qi], off, 64);
  __shared__ double sred[8][5];
  if (l == 0)
#pragma unroll
    for (int qi=0; qi<5; qi++) sred[w][qi] = v[qi];
  __syncthreads();
  if (tid == 0) {
#pragma unroll
    for (int qi=0; qi<5; qi++) {
      double s = 0.0;
#pragma unroll
      for (int ww=0; ww<8; ww++) s += sred[ww][qi];
      part1[blk*5 + qi] = s;
    }
  }
}

// ===== K5: redundant BN1 fold + per-branch o_pre max/min + BN2 partials =====
__global__ __launch_bounds__(64) void branch_k(const float* __restrict__ f,
    const float* __restrict__ dw, const double* __restrict__ part1,
    const float* __restrict__ ew1, const float* __restrict__ eb1,
    const float* __restrict__ eg1, const float* __restrict__ ebt1,
    const float* __restrict__ ew2, const float* __restrict__ eb2,
    float* __restrict__ maxo, float* __restrict__ mino,
    double* __restrict__ part2) {
  const int l = threadIdx.x;
  const int blk = blockIdx.x, br = blockIdx.y;
  double a[5] = {0,0,0,0,0};
  for (int b2 = l; b2 < 512; b2 += 64)
#pragma unroll
    for (int q=0;q<5;q++) a[q] += part1[b2*5+q];
#pragma unroll
  for (int q=0;q<5;q++)
    for (int off=32; off>0; off>>=1) a[q] += __shfl_down(a[q], off, 64);
#pragma unroll
  for (int q=0;q<5;q++) a[q] = __shfl(a[q], 0, 64);
  double Ef = a[0]/16384.0, Eff = a[1]/16384.0;
  double Ed = a[2]/MTOT, Edd = a[3]/MTOT, Efd = a[4]/MTOT;
  double Vf = Eff - Ef*Ef, Vd = Edd - Ed*Ed, Cfd = Efd - Ef*Ed;
  float sA[16], sB[16], sC[16], sW[16];
#pragma unroll
  for (int c=0;c<16;c++) {
    int idx = br*16 + c;
    double w0 = (double)ew1[idx*2+0], w1 = (double)ew1[idx*2+1];
    double b1 = (double)eb1[idx];
    double m1 = w0*Ef + w1*Ed + b1;
    double v1 = w0*w0*Vf + 2.0*w0*w1*Cfd + w1*w1*Vd;
    double r1 = 1.0 / sqrt(v1 + 1e-5);
    double g = (double)eg1[idx];
    sA[c] = (float)(g*r1*w0);
    sB[c] = (float)(g*r1*w1);
    sC[c] = (float)(g*r1*(b1 - m1) + (double)ebt1[idx]);
    sW[c] = ew2[idx];
  }
  int row = (blk << 6) + l;
  float fv = f[row];
  const float* dd = dw + (size_t)row*KN;
  float b2v = eb2[br];
  float P[16];
#pragma unroll
  for (int c=0;c<16;c++) P[c] = fmaf(sA[c], fv, sC[c]);
  float mx = -INFINITY, mn = INFINITY;
  double s = 0.0, s2 = 0.0;
  for (int k=0;k<KN;k++) {
    float d = dd[k];
    float t = b2v;
#pragma unroll
    for (int c=0;c<16;c++)
      t = fmaf(sW[c], fmaxf(fmaf(sB[c], d, P[c]), 0.f), t);
    mx = fmaxf(mx, t);
    mn = fminf(mn, t);
    double td = (double)t;
    s += td; s2 += td*td;
  }
  maxo[br*16384 + row] = mx;
  mino[br*16384 + row] = mn;
#pragma unroll
  for (int off=32; off>0; off>>=1) {
    s  += __shfl_down(s, off, 64);
    s2 += __shfl_down(s2, off, 64);
  }
  if (l == 0) {
    part2[(br*256 + blk)*2 + 0] = s;
    part2[(br*256 + blk)*2 + 1] = s2;
  }
}

// ===== K6: redundant BN2 fold + pixel shuffle + sigmoid =====
__global__ __launch_bounds__(256) void out_k(const float* __restrict__ f,
    const float* __restrict__ maxo, const float* __restrict__ mino,
    const double* __restrict__ part2,
    const float* __restrict__ eg2, const float* __restrict__ ebt2,
    float* __restrict__ out) {
  __shared__ float c2c[3][2];
  const int tid = threadIdx.x, blk = blockIdx.x;
  const int l = tid & 63, w = tid >> 6;
  if (w < 3) {
    int br = w;
    double s = 0.0, s2 = 0.0;
#pragma unroll
    for (int i=0;i<4;i++) {
      int bb = l + (i << 6);
      s  += part2[(br*256 + bb)*2 + 0];
      s2 += part2[(br*256 + bb)*2 + 1];
    }
#pragma unroll
    for (int off=32; off>0; off>>=1) {
      s  += __shfl_down(s, off, 64);
      s2 += __shfl_down(s2, off, 64);
    }
    if (l == 0) {
      double mean = s / MTOT;
      double var = s2 / MTOT - mean*mean;
      double r2 = 1.0 / sqrt(var + 1e-5);
      double sc = (double)eg2[br] * r2;
      c2c[br][0] = (float)sc;
      c2c[br][1] = (float)((double)ebt2[br] - sc*mean);
    }
  }
  __syncthreads();
  int tg = (blk << 8) + tid;     // 65536
  int bo = tg >> 14;
  int y = (tg >> 7) & 127, xx = tg & 127;
  int n = ((y>>1)<<6) + (xx>>1);
  int ch = ((y&1)<<1) + (xx&1);
  float v;
  if (ch == 0) {
    v = f[bo*NPIX + n];
  } else {
    int br = ch - 1;
    float sc = c2c[br][0], sh = c2c[br][1];
    float base = (sc >= 0.f) ? maxo[br*16384 + bo*NPIX + n]
                             : mino[br*16384 + bo*NPIX + n];
    v = fmaxf(fmaf(sc, base, sh), 0.f);
  }
  out[tg] = 1.f / (1.f + expf(-v));
}

extern "C" void kernel_launch(void* const* d_in, const int* in_sizes, int n_in,
                              void* d_out, int out_size, void* d_ws, size_t ws_size,
                              hipStream_t stream) {
  (void)in_sizes; (void)n_in; (void)out_size; (void)ws_size;
  const float* x    = (const float*)d_in[0];
  const float* c1w  = (const float*)d_in[1];
  const float* c1b  = (const float*)d_in[2];
  const float* c2w  = (const float*)d_in[3];
  const float* c2b  = (const float*)d_in[4];
  const float* c3w  = (const float*)d_in[5];
  const float* c3b  = (const float*)d_in[6];
  const float* c4w  = (const float*)d_in[7];
  const float* c4b  = (const float*)d_in[8];
  const float* ew1  = (const float*)d_in[9];
  const float* eb1  = (const float*)d_in[10];
  const float* eg1  = (const float*)d_in[11];
  const float* ebt1 = (const float*)d_in[12];
  const float* ew2  = (const float*)d_in[13];
  const float* eb2  = (const float*)d_in[14];
  const float* eg2  = (const float*)d_in[15];
  const float* ebt2 = (const float*)d_in[16];
  float* out = (float*)d_out;
  float* ws  = (float*)d_ws;

  float*  c2buf = ws;                       // 524288 floats
  float*  fbuf  = ws + 524288;              // 16384
  float*  dw    = ws + 540672;              // 327680
  float*  sval  = ws + 868352;              // 16384
  int*    sidx  = (int*)(ws + 884736);      // 16384
  float*  maxo  = ws + 901120;              // 49152
  float*  mino  = ws + 950272;              // 49152
  double* part1 = (double*)(ws + 999424);   // 512*5 doubles
  double* part2 = (double*)(ws + 1004544);  // 256*3*2 doubles

  conv12_k<<<dim3(4,64,2), 512, 0, stream>>>(x, c1w, c1b, c2w, c2b, c2buf);
  conv34_k<<<dim3(4,128), 512, 0, stream>>>(c2buf, c3w, c3b, c4w, c4b, fbuf);
  sort2_k<<<4, 1024, 0, stream>>>(fbuf, sval, sidx);
  knn4_k<<<512, 512, 0, stream>>>(fbuf, sval, sidx, dw, part1);
  branch_k<<<dim3(256,3), 64, 0, stream>>>(fbuf, dw, part1,
      ew1, eb1, eg1, ebt1, ew2, eb2, maxo, mino, part2);
  out_k<<<256, 256, 0, stream>>>(fbuf, maxo, mino, part2, eg2, ebt2, out);
}